// Round 2
// baseline (48.438 us; speedup 1.0000x reference)
//
#include <hip/hip_runtime.h>

// Problem constants (reference: B=4, L=8192, D=1024, K=7)
constexpr int B = 4;
constexpr int L = 8192;
constexpr int D = 1024;
constexpr int K = 7;
constexpr int HALF = K / 2;    // 3
constexpr int T = 16;          // l-positions per block tile (was 8)
constexpr int NROW = T + K - 1; // 22 window rows per tile
constexpr int RING = 16;       // register ring slots (power of 2 >= 14+prefetch reuse)
constexpr int NXCD = 8;

typedef float v4f __attribute__((ext_vector_type(4)));

// Block = 256 threads x v4f = all D=1024 channels, T=16 consecutive l.
// Register-ring software pipeline: rows l0-6 .. l0+15 live in a 16-slot v4f
// ring (row r -> slot r&15). 14 rows loaded up front; during output t<8 the
// load of row 14+t is issued into slot (t-2)&15, whose row died at output t-2.
// This keeps an 8-deep prefetch stream in flight under the FMA/store stream
// and cuts halo redundancy from 1.75x to 1.375x.
__global__ __launch_bounds__(256, 4)
void dynconv_kernel(const float* __restrict__ x,
                    const float* __restrict__ sb,
                    const float* __restrict__ w,
                    const float* __restrict__ bias,
                    float* __restrict__ out)
{
    // ---- XCD-chunked swizzle (bijective since 2048 % 8 == 0) ----
    constexpr int nwg = B * (L / T);        // 2048
    constexpr int cpx = nwg / NXCD;         // 256 tiles per XCD chunk
    const int bid  = blockIdx.x;
    const int tile = (bid % NXCD) * cpx + bid / NXCD;

    const int nt  = L / T;                  // tiles per batch = 512
    const int b   = tile / nt;
    const int l0  = (tile % nt) * T;
    const int tid = threadIdx.x;
    const int d0  = tid * 4;

    // ---- phase 0: first 14 window rows, all independent ----
    const float* xb = x + (size_t)b * L * D + d0;
    v4f X[RING];
    #pragma unroll
    for (int j = 0; j < 14; ++j) {
        const int l = l0 - (K - 1) + j;     // l0-6 .. l0+7 (uniform guard)
        X[j] = (l >= 0) ? *(const v4f*)(xb + (size_t)l * D)
                        : (v4f)(0.f);
    }

    // ---- weights: 28 contiguous floats per thread (4 channels x K) ----
    union { v4f q[7]; float f[28]; } wu;
    {
        const v4f* wp = (const v4f*)(w + (size_t)d0 * K); // 112B-aligned
        #pragma unroll
        for (int j = 0; j < 7; ++j) wu.q[j] = wp[j];
    }
    const v4f bv = *(const v4f*)(bias + d0);

    // ---- block-uniform mask: box-filter(boundaries, width 7), 0.5**count ----
    const float* sbb = sb + (size_t)b * L;
    float s[T + 2 * HALF];                  // positions l0-3 .. l0+18
    #pragma unroll
    for (int j = 0; j < T + 2 * HALF; ++j) {
        const int p = l0 - HALF + j;        // uniform per block
        s[j] = (p >= 0 && p < L) ? sbb[p] : 0.f;
    }
    float mask[T];
    {
        float c = 0.f;
        #pragma unroll
        for (int j = 0; j < K; ++j) c += s[j];
        mask[0] = exp2f(-c);
        #pragma unroll
        for (int t = 1; t < T; ++t) {
            c += s[t + K - 1] - s[t - 1];   // sliding box sum
            mask[t] = exp2f(-c);
        }
    }

    // ---- main loop: prefetch rows 14..21 under outputs 0..7 ----
    float* ob = out + ((size_t)b * L + (size_t)l0) * D + d0;
    #pragma unroll
    for (int t = 0; t < T; ++t) {
        if (t < NROW - 14) {                // t < 8: prefetch row 14+t
            const int r = 14 + t;           // row index; l = l0+8+t, always in [8, L)
            X[r & (RING - 1)] = *(const v4f*)(xb + (size_t)(l0 + 8 + t) * D);
        }
        v4f acc = bv;
        #pragma unroll
        for (int k = 0; k < K; ++k) {
            // wv[k][c] = w[(d0+c)*K + k] = wu.f[c*7 + k]
            v4f wk = { wu.f[0 * K + k], wu.f[1 * K + k],
                       wu.f[2 * K + k], wu.f[3 * K + k] };
            acc += wk * X[(t + k) & (RING - 1)];
        }
        acc *= mask[t];
        __builtin_nontemporal_store(acc, (v4f*)(ob + (size_t)t * D));
    }
}

extern "C" void kernel_launch(void* const* d_in, const int* in_sizes, int n_in,
                              void* d_out, int out_size, void* d_ws, size_t ws_size,
                              hipStream_t stream)
{
    const float* x    = (const float*)d_in[0];  // (B, L, D)
    const float* sb   = (const float*)d_in[1];  // (B, L)
    const float* w    = (const float*)d_in[2];  // (D, 1, K)
    const float* bias = (const float*)d_in[3];  // (D,)
    float* out = (float*)d_out;                 // (B, L, D)

    const int blocks = B * (L / T);             // 2048
    dynconv_kernel<<<blocks, 256, 0, stream>>>(x, sb, w, bias, out);
}

// Round 4
// 46.978 us; speedup vs baseline: 1.0311x; 1.0311x over previous
//
#include <hip/hip_runtime.h>

// Problem constants (reference: B=4, L=8192, D=1024, K=7)
constexpr int B = 4;
constexpr int L = 8192;
constexpr int D = 1024;
constexpr int K = 7;
constexpr int HALF = K / 2;    // 3
constexpr int T = 8;           // l-positions per phase
constexpr int P = 4;           // phases (tiles) per block
constexpr int SPAN = T * P;    // 32 l-positions per block
constexpr int WROW = T + K - 1; // 14 live window rows
constexpr int NXCD = 8;

typedef float v4f __attribute__((ext_vector_type(4)));

// Persistent multi-tile blocks: grid 1024, each block = 256 threads x v4f
// (all D=1024 channels) x 32 consecutive l, processed as 4 phases of 8.
// A 14-row register window shifts by 8 each phase: consecutive tiles share
// 6 halo rows in REGISTERS (logical read amplification 1.75x -> 1.19x), and
// each phase prefetches the next 8 rows before its FMAs, keeping the load
// stream dense across the whole block lifetime (4x longer waves, 4x fewer
// WG launches). All array indices are compile-time after unrolling.
__global__ __launch_bounds__(256, 3)
void dynconv_kernel(const float* __restrict__ x,
                    const float* __restrict__ sb,
                    const float* __restrict__ w,
                    const float* __restrict__ bias,
                    float* __restrict__ out)
{
    // ---- XCD-chunked swizzle (bijective since 1024 % 8 == 0) ----
    constexpr int nwg = B * (L / SPAN);     // 1024
    constexpr int cpx = nwg / NXCD;         // 128
    const int bid = blockIdx.x;
    const int st  = (bid % NXCD) * cpx + bid / NXCD;

    const int spb = L / SPAN;               // 256 supertiles per batch
    const int b   = st / spb;
    const int l0  = (st % spb) * SPAN;
    const int tid = threadIdx.x;
    const int d0  = tid * 4;

    // ---- uniform data: weights (28 floats/thread), bias ----
    union { v4f q[7]; float f[28]; } wu;
    {
        const v4f* wp = (const v4f*)(w + (size_t)d0 * K); // 112B-aligned
        #pragma unroll
        for (int j = 0; j < 7; ++j) wu.q[j] = wp[j];
    }
    const v4f bv = *(const v4f*)(bias + d0);

    const float* xb  = x  + (size_t)b * L * D + d0;
    const float* sbb = sb + (size_t)b * L;
    float*       ob  = out + ((size_t)b * L + (size_t)l0) * D + d0;

    // ---- initial window: rows l0-6 .. l0+7 ----
    v4f Wn[WROW];
    #pragma unroll
    for (int j = 0; j < WROW; ++j) {
        const int l = l0 - (K - 1) + j;     // uniform guard (only l0==0 clips)
        Wn[j] = (l >= 0) ? *(const v4f*)(xb + (size_t)l * D)
                         : (v4f)(0.f);
    }

    #pragma unroll
    for (int p = 0; p < P; ++p) {
        const int lp = l0 + p * T;

        // ---- prefetch next phase's rows lp+8 .. lp+15 (always in [8, L)) ----
        v4f N[T];
        if (p < P - 1) {
            #pragma unroll
            for (int i = 0; i < T; ++i)
                N[i] = *(const v4f*)(xb + (size_t)(lp + T + i) * D);
        }

        // ---- block-uniform mask for this phase (sb is tiny, L2-hot) ----
        float s[T + 2 * HALF];
        #pragma unroll
        for (int j = 0; j < T + 2 * HALF; ++j) {
            const int q = lp - HALF + j;    // uniform per block
            s[j] = (q >= 0 && q < L) ? sbb[q] : 0.f;
        }
        float mask[T];
        {
            float c = 0.f;
            #pragma unroll
            for (int j = 0; j < K; ++j) c += s[j];
            mask[0] = exp2f(-c);
            #pragma unroll
            for (int t = 1; t < T; ++t) {
                c += s[t + K - 1] - s[t - 1];
                mask[t] = exp2f(-c);
            }
        }

        // ---- compute + streaming stores (validated builtin nt) ----
        #pragma unroll
        for (int t = 0; t < T; ++t) {
            v4f acc = bv;
            #pragma unroll
            for (int k = 0; k < K; ++k) {
                // wv[k][c] = w[(d0+c)*K + k] = wu.f[c*7 + k]
                v4f wk = { wu.f[0 * K + k], wu.f[1 * K + k],
                           wu.f[2 * K + k], wu.f[3 * K + k] };
                acc += wk * Wn[t + k];
            }
            acc *= mask[t];
            __builtin_nontemporal_store(acc, (v4f*)(ob + (size_t)(p * T + t) * D));
        }

        // ---- shift window by 8 rows (static indices; cheap v_movs) ----
        if (p < P - 1) {
            #pragma unroll
            for (int j = 0; j < WROW - T; ++j) Wn[j] = Wn[j + T];
            #pragma unroll
            for (int i = 0; i < T; ++i)       Wn[WROW - T + i] = N[i];
        }
    }
}

extern "C" void kernel_launch(void* const* d_in, const int* in_sizes, int n_in,
                              void* d_out, int out_size, void* d_ws, size_t ws_size,
                              hipStream_t stream)
{
    const float* x    = (const float*)d_in[0];  // (B, L, D)
    const float* sb   = (const float*)d_in[1];  // (B, L)
    const float* w    = (const float*)d_in[2];  // (D, 1, K)
    const float* bias = (const float*)d_in[3];  // (D,)
    float* out = (float*)d_out;                 // (B, L, D)

    const int blocks = B * (L / SPAN);          // 1024
    dynconv_kernel<<<blocks, 256, 0, stream>>>(x, sb, w, bias, out);
}

// Round 5
// 44.145 us; speedup vs baseline: 1.0972x; 1.0642x over previous
//
#include <hip/hip_runtime.h>

// Problem constants (reference: B=4, L=8192, D=1024, K=7)
constexpr int B = 4;
constexpr int L = 8192;
constexpr int D = 1024;
constexpr int K = 7;
constexpr int HALF = K / 2;   // 3
constexpr int T = 8;          // l-positions per block tile (best verified: R1, 43.8 us)
constexpr int W = T + K - 1;  // 14 float4 window loads per thread
constexpr int NXCD = 8;

typedef float v4f __attribute__((ext_vector_type(4)));

// Block = 256 threads x v4f = all D=1024 channels, T=8 consecutive l.
// R1 structure (best verified): no LDS, no barrier, block-uniform mask
// computed per-thread (sliding box sum), XCD-chunked bijective swizzle,
// builtin nontemporal stores. One change vs R1: uniform loads (weights,
// bias, sb) issued BEFORE the x window loads so the first output's FMA
// chain waits only on x rows 0..6, not the whole load queue.
//
// Fabric-roofline note: irreducible L2-miss traffic = 134 MB x-read +
// 131 MB out-write = 265 MB; at the 6.29 TB/s copy ceiling that is 42.1 us.
// R1 measured 43.8 us = 96% of that ceiling.
__global__ __launch_bounds__(256, 4)
void dynconv_kernel(const float* __restrict__ x,
                    const float* __restrict__ sb,
                    const float* __restrict__ w,
                    const float* __restrict__ bias,
                    float* __restrict__ out)
{
    // ---- XCD-chunked swizzle (bijective since 4096 % 8 == 0) ----
    constexpr int nwg = B * (L / T);        // 4096
    constexpr int cpx = nwg / NXCD;         // 512 tiles per XCD chunk
    const int bid  = blockIdx.x;
    const int tile = (bid % NXCD) * cpx + bid / NXCD;

    const int nt  = L / T;                  // tiles per batch = 1024
    const int b   = tile / nt;
    const int l0  = (tile % nt) * T;
    const int tid = threadIdx.x;
    const int d0  = tid * 4;

    // ---- uniform loads first: weights, bias, boundary window ----
    union { v4f q[7]; float f[28]; } wu;
    {
        const v4f* wp = (const v4f*)(w + (size_t)d0 * K); // 112B-aligned
        #pragma unroll
        for (int j = 0; j < 7; ++j) wu.q[j] = wp[j];
    }
    const v4f bv = *(const v4f*)(bias + d0);

    const float* sbb = sb + (size_t)b * L;
    float s[T + 2 * HALF];                  // positions l0-3 .. l0+10
    #pragma unroll
    for (int j = 0; j < T + 2 * HALF; ++j) {
        const int p = l0 - HALF + j;        // uniform per block
        s[j] = (p >= 0 && p < L) ? sbb[p] : 0.f;
    }

    // ---- window loads: x[b, l0-6 .. l0+T-1, d0:d0+4], all independent ----
    const float* xb = x + (size_t)b * L * D + d0;
    v4f X[W];
    #pragma unroll
    for (int j = 0; j < W; ++j) {
        const int l = l0 - (K - 1) + j;     // uniform condition per j
        X[j] = (l >= 0) ? *(const v4f*)(xb + (size_t)l * D)
                        : (v4f)(0.f);
    }

    // ---- block-uniform mask: box-filter(boundaries, width 7), 0.5**count ----
    float mask[T];
    {
        float c = 0.f;
        #pragma unroll
        for (int j = 0; j < K; ++j) c += s[j];
        mask[0] = exp2f(-c);
        #pragma unroll
        for (int t = 1; t < T; ++t) {
            c += s[t + K - 1] - s[t - 1];   // sliding box sum
            mask[t] = exp2f(-c);
        }
    }

    // ---- compute + streaming stores ----
    float* ob = out + ((size_t)b * L + (size_t)l0) * D + d0;
    #pragma unroll
    for (int t = 0; t < T; ++t) {
        v4f acc = bv;
        #pragma unroll
        for (int k = 0; k < K; ++k) {
            // wv[k][c] = w[(d0+c)*K + k] = wu.f[c*7 + k]
            v4f wk = { wu.f[0 * K + k], wu.f[1 * K + k],
                       wu.f[2 * K + k], wu.f[3 * K + k] };
            acc += wk * X[t + k];
        }
        acc *= mask[t];
        __builtin_nontemporal_store(acc, (v4f*)(ob + (size_t)t * D));
    }
}

extern "C" void kernel_launch(void* const* d_in, const int* in_sizes, int n_in,
                              void* d_out, int out_size, void* d_ws, size_t ws_size,
                              hipStream_t stream)
{
    const float* x    = (const float*)d_in[0];  // (B, L, D)
    const float* sb   = (const float*)d_in[1];  // (B, L)
    const float* w    = (const float*)d_in[2];  // (D, 1, K)
    const float* bias = (const float*)d_in[3];  // (D,)
    float* out = (float*)d_out;                 // (B, L, D)

    const int blocks = B * (L / T);             // 4096
    dynconv_kernel<<<blocks, 256, 0, stream>>>(x, sb, w, bias, out);
}